// Round 4
// baseline (6983.514 us; speedup 1.0000x reference)
//
#include <hip/hip_runtime.h>
#include <math.h>

// LstmCellRudder persistent MFMA kernel, round 11.
// B=256, T=512, D=160 (obs128+act32), H=512, gates 4H=2048, K=672.
// Grid 256 blocks x 256 threads (4 waves, 1 block/CU). 16 bgrps x 16 blocks,
// XCD-pure runtime negotiation (verified R4-R6).
// NEW vs R10 (counters showed publishes/loads are serviced at the
// Infinity Cache: WRITE_SIZE == publish volume; each ring hop is a
// ~600-900cy memory-side round trip, and R10's chain had THREE):
//  - TAG-IN-DATA publish: producer stores ONE 8B atomic {tag=t+1, h-pair}.
//    Consumers spin on the very 8B entries they feed to MFMA - detection
//    and data arrive in the same load. Deletes flag array, producer
//    vmcnt(0), flag poll hop, and the separate data load: 3 hops -> 1.
//  - ZERO barriers in the main loop: each wave self-synchronizes on tags.
//    Safety by induction: block publishes tag t+1 only after consuming all
//    tag-t entries, so tag-t can't be overwritten (tag t+2, same parity
//    buffer) until every reader of t is done. y-gather reads placed BEFORE
//    the publish to stay inside that window.
//  - x fragments loaded per-lane straight from obs/act into registers
//    (cached loads, issued one step ahead); x LDS + its barrier deleted.
//  - y dot rotates across waves (w == t&3); reduce+store post-publish.
// Tagged h layout per bgrp per buffer: [16 ck][64 slot][4 qe] x 8B = 32KB.
// slot = q*16 + (b ^ ck); entry qe holds halves e=2qe,2qe+1 (h[b][ck*32+q*8+e]).

namespace {
constexpr int kT = 512, kH = 512;

typedef _Float16 v8h __attribute__((ext_vector_type(8)));
typedef float v4f __attribute__((ext_vector_type(4)));
typedef unsigned v4u __attribute__((ext_vector_type(4)));
typedef unsigned long long ull;

__device__ __forceinline__ ull ld64sc(const ull* p, bool sys) {
    return sys ? __hip_atomic_load(p, __ATOMIC_RELAXED, __HIP_MEMORY_SCOPE_SYSTEM)
               : __hip_atomic_load(p, __ATOMIC_RELAXED, __HIP_MEMORY_SCOPE_AGENT);
}
__device__ __forceinline__ void st64sc(ull* p, ull v, bool sys) {
    if (sys) __hip_atomic_store(p, v, __ATOMIC_RELAXED, __HIP_MEMORY_SCOPE_SYSTEM);
    else     __hip_atomic_store(p, v, __ATOMIC_RELAXED, __HIP_MEMORY_SCOPE_AGENT);
}
__device__ __forceinline__ unsigned ld_sys32(const unsigned* p) {
    return __hip_atomic_load(p, __ATOMIC_RELAXED, __HIP_MEMORY_SCOPE_SYSTEM);
}

// exp2-based, clamp-free: exact at +-inf (exp2->{0,inf}, rcp(inf)=0).
__device__ __forceinline__ float sigf(float x) {
    return __builtin_amdgcn_rcpf(1.0f + __builtin_amdgcn_exp2f(x * -1.442695041f));
}
__device__ __forceinline__ float tanhff(float x) {
    return fmaf(-2.0f,
                __builtin_amdgcn_rcpf(__builtin_amdgcn_exp2f(x * 2.885390082f) + 1.0f),
                1.0f);
}

// h0 -> tagged fragment layout in hfA (tag 0); hfB entries tagged 0 (dummy).
__global__ void lstm_init(const float* __restrict__ h0, ull* __restrict__ hfA,
                          ull* __restrict__ hfB, unsigned* __restrict__ ctrl) {
    int i = blockIdx.x * blockDim.x + threadIdx.x;  // 65536 = B*H/2
    int bb = i >> 8, pr = i & 255;
    int j0 = pr * 2;
    int ck = j0 >> 5, jl = j0 & 31, qf = jl >> 3, qe = (jl & 7) >> 1;
    int bgrp = bb >> 4, b = bb & 15;
    int slot = qf * 16 + (b ^ ck);
    size_t off = (size_t)bgrp * 4096 + ck * 256 + slot * 4 + qe;
    union { unsigned u; _Float16 h[2]; } pk;
    pk.h[0] = (_Float16)h0[(size_t)bb * kH + j0];
    pk.h[1] = (_Float16)h0[(size_t)bb * kH + j0 + 1];
    hfA[off] = (ull)pk.u;   // hi32 tag = 0, lo32 = h pair
    hfB[off] = 0ull;        // tag 0, dummy data (parity-1 targets are odd)
    if (i < 16) ctrl[1024 + i] = 0u;  // regcnt[8] + regtotal
}

__global__ __launch_bounds__(256, 1) void lstm_persist(
    const float* __restrict__ obs, const float* __restrict__ act,
    const float* __restrict__ Wih, const float* __restrict__ Whh,
    const float* __restrict__ bih, const float* __restrict__ bhh,
    const float* __restrict__ Wout, const float* __restrict__ bout_p,
    const float* __restrict__ c0,
    ull* __restrict__ hfA, ull* __restrict__ hfB,
    unsigned* __restrict__ ctrl, float* __restrict__ out) {

    __shared__ float ytail[2];
    __shared__ int sh_role[3];  // bgrp, jg, sys

    const int tid = threadIdx.x;
    const int w = tid >> 6, ln = tid & 63;   // 4 waves
    const int lm = ln & 15, q = ln >> 4;     // MFMA lane decomposition

    unsigned* regcnt = ctrl + 1024;      // [8]
    unsigned* regtotal = ctrl + 1032;    // [1]

    // ---- runtime XCD-aware role negotiation (one-time, verified R6) ----
    if (tid == 0) {
        int x = __builtin_amdgcn_s_getreg(20 | (31 << 11)) & 7;  // HW_REG_XCC_ID
        unsigned slot = atomicAdd(&regcnt[x], 1u);
        asm volatile("s_waitcnt vmcnt(0)" ::: "memory");
        atomicAdd(regtotal, 1u);
        while (ld_sys32(regtotal) < 256u) __builtin_amdgcn_s_sleep(8);
        unsigned cnt[8];
#pragma unroll
        for (int i = 0; i < 8; ++i) cnt[i] = ld_sys32(&regcnt[i]);
        int pure_base = 0, total_pure = 0, lbase = 0;
        for (int i = 0; i < 8; ++i) {
            if (i < x) { pure_base += cnt[i] >> 4; lbase += cnt[i] & 15; }
            total_pure += cnt[i] >> 4;
        }
        int px16 = (int)(cnt[x] >> 4) * 16;
        int bg, jv, sv;
        if ((int)slot < px16) {
            bg = pure_base + ((int)slot >> 4); jv = slot & 15; sv = 0;
        } else {
            int lr = lbase + ((int)slot - px16);
            bg = total_pure + (lr >> 4); jv = lr & 15; sv = 1;
        }
        sh_role[0] = bg; sh_role[1] = jv; sh_role[2] = sv;
    }
    __syncthreads();
    const int bgrp = sh_role[0], jg = sh_role[1];
    const bool sysS = sh_role[2] != 0;
    const int yb = bgrp * 16 + jg;

    // ---- persistent A fragments: wave w -> j-local = w*8 + jj*2 + ti ----
    v8h afrag[2][21];
    {
        const int jj = lm >> 2, gt = lm & 3;
#pragma unroll
        for (int ti = 0; ti < 2; ++ti) {
            const int grow = gt * kH + jg * 32 + w * 8 + jj * 2 + ti;
#pragma unroll
            for (int kc = 0; kc < 21; ++kc) {
                const int k0 = kc * 32 + q * 8;
                const float* src = (k0 < 160) ? (Wih + grow * 160 + k0)
                                              : (Whh + (size_t)grow * kH + (k0 - 160));
                float4 A = *(const float4*)src;
                float4 Bv = *(const float4*)(src + 4);
                v8h f;
                f[0] = (_Float16)A.x;  f[1] = (_Float16)A.y;
                f[2] = (_Float16)A.z;  f[3] = (_Float16)A.w;
                f[4] = (_Float16)Bv.x; f[5] = (_Float16)Bv.y;
                f[6] = (_Float16)Bv.z; f[7] = (_Float16)Bv.w;
                afrag[ti][kc] = f;
            }
        }
    }
    float biasv[2][4];
    float creg[2];
#pragma unroll
    for (int ti = 0; ti < 2; ++ti) {
        const int jloc = jg * 32 + w * 8 + q * 2 + ti;
#pragma unroll
        for (int g = 0; g < 4; ++g)
            biasv[ti][g] = bih[g * kH + jloc] + bhh[g * kH + jloc];
        creg[ti] = c0[(size_t)(bgrp * 16 + lm) * kH + jloc];
    }

    const float bout0 = bout_p[0];
    // y gather identity: lane ln covers j = (ln>>2)*32 + (ln&3)*8 + e(0..7)
    const int yck = ln >> 2, yqf = ln & 3;
    float ywt[8];
#pragma unroll
    for (int e = 0; e < 8; ++e) ywt[e] = Wout[yck * 32 + yqf * 8 + e];
    float4 wout4 = make_float4(0.f, 0.f, 0.f, 0.f);
    if (tid < 128) wout4 = *(const float4*)(Wout + tid * 4);

    // ---- x register pipeline: per-lane direct fragment loads ----
    // lane (q,lm): batch row b = lm, k = kc*32 + q*8 .. +7 (kc 0..3 obs, 4 act)
    float4 xs[10];
    v8h xc[5];
    const size_t browb = (size_t)(bgrp * 16 + lm) * kT;
    auto x_issue = [&](int tt) {
#pragma unroll
        for (int kc = 0; kc < 5; ++kc) {
            const int k0 = kc * 32 + q * 8;
            const float* p = (kc < 4) ? (obs + (browb + tt) * 128 + k0)
                                      : (act + (browb + tt) * 32 + (k0 - 128));
            xs[2 * kc]     = *(const float4*)(p);
            xs[2 * kc + 1] = *(const float4*)(p + 4);
        }
    };
    auto x_cvt = [&]() {
#pragma unroll
        for (int kc = 0; kc < 5; ++kc) {
            float4 a = xs[2 * kc], b = xs[2 * kc + 1];
            v8h f;
            f[0] = (_Float16)a.x; f[1] = (_Float16)a.y;
            f[2] = (_Float16)a.z; f[3] = (_Float16)a.w;
            f[4] = (_Float16)b.x; f[5] = (_Float16)b.y;
            f[6] = (_Float16)b.z; f[7] = (_Float16)b.w;
            xc[kc] = f;
        }
    };

    // preloop: x(0) into regs
    x_issue(0);
    x_cvt();

#pragma unroll 1
    for (int t = 0; t < kT; ++t) {
        const ull* hs = ((t & 1) ? hfB : hfA) + (size_t)bgrp * 4096;
        ull* hd = ((t & 1) ? hfA : hfB) + (size_t)bgrp * 4096;
        const unsigned tg = (unsigned)t;

        // ---- 1. issue all 64 tagged h-entry loads (16 chunks x 4) ----
        ull e0[16], e1[16], e2[16], e3[16];
#pragma unroll
        for (int ck = 0; ck < 16; ++ck) {
            const ull* sp = hs + ck * 256 + (ln ^ ck) * 4;
            e0[ck] = ld64sc(sp + 0, sysS);
            e1[ck] = ld64sc(sp + 1, sysS);
            e2[ck] = ld64sc(sp + 2, sysS);
            e3[ck] = ld64sc(sp + 3, sysS);
        }
        // y-turn (rotates across waves): issue 4 tagged loads
        const bool yt = (t > 0) && (w == (t & 3));
        const ull* yp = hs + yck * 256 + (yqf * 16 + (jg ^ yck)) * 4;
        ull y0 = 0, y1 = 0, y2 = 0, y3 = 0;
        if (yt) {
            y0 = ld64sc(yp + 0, sysS); y1 = ld64sc(yp + 1, sysS);
            y2 = ld64sc(yp + 2, sysS); y3 = ld64sc(yp + 3, sysS);
        }

        // ---- 2. issue x loads for t+1 (hidden under h spin) ----
        if (t < kT - 1) x_issue(t + 1);

        // ---- 3. x-part MFMA from registers ----
        v4f a0 = {biasv[0][0], biasv[0][1], biasv[0][2], biasv[0][3]};
        v4f a1 = {biasv[1][0], biasv[1][1], biasv[1][2], biasv[1][3]};
#pragma unroll
        for (int kc = 0; kc < 5; ++kc) {
            a0 = __builtin_amdgcn_mfma_f32_16x16x32_f16(afrag[0][kc], xc[kc], a0, 0, 0, 0);
            a1 = __builtin_amdgcn_mfma_f32_16x16x32_f16(afrag[1][kc], xc[kc], a1, 0, 0, 0);
        }

        // ---- 4. h chunks: spin-on-tag + MFMA (split-K chains) ----
        v4f b0 = {0.f, 0.f, 0.f, 0.f}, b1 = {0.f, 0.f, 0.f, 0.f};
#pragma unroll
        for (int ck = 0; ck < 16; ++ck) {
            const ull* sp = hs + ck * 256 + (ln ^ ck) * 4;
            while (true) {
                unsigned d = ((unsigned)(e0[ck] >> 32) ^ tg) |
                             ((unsigned)(e1[ck] >> 32) ^ tg) |
                             ((unsigned)(e2[ck] >> 32) ^ tg) |
                             ((unsigned)(e3[ck] >> 32) ^ tg);
                if (__all((int)(d == 0u))) break;
                e0[ck] = ld64sc(sp + 0, sysS);
                e1[ck] = ld64sc(sp + 1, sysS);
                e2[ck] = ld64sc(sp + 2, sysS);
                e3[ck] = ld64sc(sp + 3, sysS);
            }
            v4u pu = {(unsigned)e0[ck], (unsigned)e1[ck],
                      (unsigned)e2[ck], (unsigned)e3[ck]};
            v8h bfr = __builtin_bit_cast(v8h, pu);
            if (ck < 8) {
                a0 = __builtin_amdgcn_mfma_f32_16x16x32_f16(afrag[0][5 + ck], bfr, a0, 0, 0, 0);
                a1 = __builtin_amdgcn_mfma_f32_16x16x32_f16(afrag[1][5 + ck], bfr, a1, 0, 0, 0);
            } else {
                b0 = __builtin_amdgcn_mfma_f32_16x16x32_f16(afrag[0][5 + ck], bfr, b0, 0, 0, 0);
                b1 = __builtin_amdgcn_mfma_f32_16x16x32_f16(afrag[1][5 + ck], bfr, b1, 0, 0, 0);
            }
        }

        // ---- 5. y spin + dot (PRE-publish: reads must precede our t+1) ----
        float ydot = 0.f;
        if (yt) {
            while (true) {
                unsigned d = ((unsigned)(y0 >> 32) ^ tg) | ((unsigned)(y1 >> 32) ^ tg) |
                             ((unsigned)(y2 >> 32) ^ tg) | ((unsigned)(y3 >> 32) ^ tg);
                if (__all((int)(d == 0u))) break;
                y0 = ld64sc(yp + 0, sysS); y1 = ld64sc(yp + 1, sysS);
                y2 = ld64sc(yp + 2, sysS); y3 = ld64sc(yp + 3, sysS);
            }
            union { unsigned u; _Float16 h[2]; } c0v, c1v, c2v, c3v;
            c0v.u = (unsigned)y0; c1v.u = (unsigned)y1;
            c2v.u = (unsigned)y2; c3v.u = (unsigned)y3;
            ydot = (float)c0v.h[0] * ywt[0] + (float)c0v.h[1] * ywt[1] +
                   (float)c1v.h[0] * ywt[2] + (float)c1v.h[1] * ywt[3] +
                   (float)c2v.h[0] * ywt[4] + (float)c2v.h[1] * ywt[5] +
                   (float)c3v.h[0] * ywt[6] + (float)c3v.h[1] * ywt[7];
        }

        // ---- 6. epilogue + single tagged 8B publish ----
        union { unsigned u32; _Float16 h2[2]; } pk;
#pragma unroll
        for (int ti = 0; ti < 2; ++ti) {
            v4f a = ti ? (a1 + b1) : (a0 + b0);
            float iv = sigf(a[0]), fv = sigf(a[1]);
            float gv = tanhff(a[2]), ov = sigf(a[3]);
            creg[ti] = fmaf(fv, creg[ti], iv * gv);
            pk.h2[ti] = (_Float16)(ov * tanhff(creg[ti]));
        }
        const ull pv = ((ull)(tg + 1) << 32) | (ull)pk.u32;
        st64sc(hd + jg * 256 + (w * 16 + (lm ^ jg)) * 4 + q, pv, sysS);

        // ---- 7. y reduce + out store (post-publish, off critical path) ----
        if (yt) {
#pragma unroll
            for (int s = 32; s; s >>= 1) ydot += __shfl_xor(ydot, s);
            if (ln == 0) out[(size_t)yb * kT + (t - 1)] = ydot + bout0;
        }

        // ---- 8. convert x(t+1) for next step ----
        if (t < kT - 1) x_cvt();
    }

    // ---- tail: out[511] from h(512) (tag 512, parity-0 buffer = hfA) ----
    if (tid < 128) {
        const int j0 = tid * 4;
        const int ck = j0 >> 5, jl = j0 & 31, qf = jl >> 3, qe0 = (jl & 7) >> 1;
        const ull* tp = hfA + (size_t)bgrp * 4096 + ck * 256 +
                        (qf * 16 + (jg ^ ck)) * 4 + qe0;
        ull u0, u1;
        while (true) {
            u0 = ld64sc(tp + 0, sysS);
            u1 = ld64sc(tp + 1, sysS);
            unsigned d = ((unsigned)(u0 >> 32) ^ 512u) | ((unsigned)(u1 >> 32) ^ 512u);
            if (__all((int)(d == 0u))) break;
        }
        union { unsigned u; _Float16 h[2]; } a0v, a1v;
        a0v.u = (unsigned)u0; a1v.u = (unsigned)u1;
        float p = (float)a0v.h[0] * wout4.x + (float)a0v.h[1] * wout4.y +
                  (float)a1v.h[0] * wout4.z + (float)a1v.h[1] * wout4.w;
#pragma unroll
        for (int s = 32; s; s >>= 1) p += __shfl_xor(p, s);
        if (ln == 0) ytail[w] = p;
    }
    __syncthreads();
    if (tid == 0) out[(size_t)yb * kT + (kT - 1)] = ytail[0] + ytail[1] + bout0;
}

}  // namespace

extern "C" void kernel_launch(void* const* d_in, const int* in_sizes, int n_in,
                              void* d_out, int out_size, void* d_ws, size_t ws_size,
                              hipStream_t stream) {
    const float* obs  = (const float*)d_in[0];
    const float* act  = (const float*)d_in[1];
    const float* Wih  = (const float*)d_in[2];
    const float* Whh  = (const float*)d_in[3];
    const float* bih  = (const float*)d_in[4];
    const float* bhh  = (const float*)d_in[5];
    const float* Wout = (const float*)d_in[6];
    const float* bout = (const float*)d_in[7];
    const float* h0   = (const float*)d_in[8];
    const float* c0   = (const float*)d_in[9];
    float* out = (float*)d_out;

    char* ws = (char*)d_ws;
    ull* hfA = (ull*)ws;                       // tagged frag h, 512 KB
    ull* hfB = (ull*)(ws + 524288);            // tagged frag h, 512 KB
    unsigned* ctrl = (unsigned*)(ws + 1048576);  // regcnt[8] + regtotal @ +1024

    lstm_init<<<256, 256, 0, stream>>>(h0, hfA, hfB, ctrl);
    lstm_persist<<<256, 256, 0, stream>>>(obs, act, Wih, Whh, bih, bhh, Wout, bout,
                                          c0, hfA, hfB, ctrl, out);
}

// Round 5
// 1314.649 us; speedup vs baseline: 5.3121x; 5.3121x over previous
//
#include <hip/hip_runtime.h>
#include <math.h>

// LstmCellRudder persistent MFMA kernel, round 12.
// B=256, T=512, D=160 (obs128+act32), H=512, gates 4H=2048, K=672.
// Grid 256 blocks x 256 threads (4 waves, 1 block/CU). 16 bgrps x 16 blocks,
// XCD-pure runtime negotiation (verified R4-R6).
// R11 post-mortem: distributed tag-spinning = one full-latency scoped load
// per spin per chunk, serialized -> 6983us. Reverted to R9 structure.
// NEW vs R9 (single surgical change):
//  - XCD-pure groups exchange through their SHARED PER-XCD L2, not the
//    Infinity Cache: ring STORES (publish + flags) are WORKGROUP-scope
//    relaxed atomics -> plain global_store -> write-back line in L2.
//    Ring LOADS stay agent-scope (sc0: L1-bypass, L2-hit). R10's counters
//    proved agent-scope stores write through L2 (WRITE_SIZE == publish
//    volume), making every publish ack + flag hop a ~600-900cy memory-side
//    round trip and contending 256 blocks on IF$ ports each step.
//    vmcnt(0) between publish and flag now acks from L2 (~150cy).
//  - mixed groups keep the SYSTEM-scope fallback (unchanged, correct).

namespace {
constexpr int kT = 512, kH = 512;

typedef _Float16 v8h __attribute__((ext_vector_type(8)));
typedef float v4f __attribute__((ext_vector_type(4)));
typedef unsigned long long ull;
typedef ull v2u __attribute__((ext_vector_type(2)));

// Ring loads: L1-bypass. sys -> IF$-coherent; pure -> served by shared L2.
__device__ __forceinline__ ull ld64sc(const ull* p, bool sys) {
    return sys ? __hip_atomic_load(p, __ATOMIC_RELAXED, __HIP_MEMORY_SCOPE_SYSTEM)
               : __hip_atomic_load(p, __ATOMIC_RELAXED, __HIP_MEMORY_SCOPE_AGENT);
}
__device__ __forceinline__ unsigned ld32sc(const unsigned* p, bool sys) {
    return sys ? __hip_atomic_load(p, __ATOMIC_RELAXED, __HIP_MEMORY_SCOPE_SYSTEM)
               : __hip_atomic_load(p, __ATOMIC_RELAXED, __HIP_MEMORY_SCOPE_AGENT);
}
// Ring stores: pure groups stay in the shared XCD L2 (write-back, plain
// global_store via WORKGROUP scope); mixed groups write through (SYSTEM).
__device__ __forceinline__ void st32sc(unsigned* p, unsigned v, bool sys) {
    if (sys) __hip_atomic_store(p, v, __ATOMIC_RELAXED, __HIP_MEMORY_SCOPE_SYSTEM);
    else     __hip_atomic_store(p, v, __ATOMIC_RELAXED, __HIP_MEMORY_SCOPE_WORKGROUP);
}
__device__ __forceinline__ unsigned ld_sys32(const unsigned* p) {
    return __hip_atomic_load(p, __ATOMIC_RELAXED, __HIP_MEMORY_SCOPE_SYSTEM);
}

// exp2-based, clamp-free: exact at +-inf (exp2->{0,inf}, rcp(inf)=0).
__device__ __forceinline__ float sigf(float x) {
    return __builtin_amdgcn_rcpf(1.0f + __builtin_amdgcn_exp2f(x * -1.442695041f));
}
__device__ __forceinline__ float tanhff(float x) {
    return fmaf(-2.0f,
                __builtin_amdgcn_rcpf(__builtin_amdgcn_exp2f(x * 2.885390082f) + 1.0f),
                1.0f);
}

// h0 -> fragment-layout hfA: per bgrp 16KB; chunk ck (=j>>5) at ck*1024;
// slot = (qf*16 + b) ^ ck holds halfs e=0..7 = h[b][ck*32 + qf*8 + e].
__global__ void lstm_init(const float* __restrict__ h0, _Float16* __restrict__ hfA,
                          unsigned* __restrict__ ctrl) {
    int i = blockIdx.x * blockDim.x + threadIdx.x;  // 131072 = B*H
    int bb = i >> 9, j = i & 511;
    int bgrp = bb >> 4, b = bb & 15;
    int ck = j >> 5, jl = j & 31, qf = jl >> 3, e = jl & 7;
    int slot = (qf * 16 + b) ^ ck;
    hfA[bgrp * 8192 + ck * 512 + slot * 8 + e] = (_Float16)h0[i];
    if (i < 1152) ctrl[i] = 0u;  // flags[16*64] + regcnt[8] + regtotal
}

__global__ __launch_bounds__(256, 1) void lstm_persist(
    const float* __restrict__ obs, const float* __restrict__ act,
    const float* __restrict__ Wih, const float* __restrict__ Whh,
    const float* __restrict__ bih, const float* __restrict__ bhh,
    const float* __restrict__ Wout, const float* __restrict__ bout_p,
    const float* __restrict__ c0,
    _Float16* __restrict__ hfA, _Float16* __restrict__ hfB,
    unsigned* __restrict__ ctrl, float* __restrict__ out) {

    // LDS: x double buffer 2x5KB, h fragment double buffer 2x16KB.
    __shared__ __align__(16) char xbuf[2][5 * 1024];
    __shared__ __align__(16) char hbuf[2][16 * 1024];
    __shared__ float ypart[2][4];
    __shared__ float ytail[2];
    __shared__ int sh_role[3];  // bgrp, jg, sys

    const int tid = threadIdx.x;
    const int w = tid >> 6, ln = tid & 63;   // 4 waves
    const int lm = ln & 15, q = ln >> 4;     // MFMA lane decomposition

    unsigned* flags = ctrl;              // [16 bgrps][64] (one per producer wave)
    unsigned* regcnt = ctrl + 1024;      // [8]
    unsigned* regtotal = ctrl + 1032;    // [1]

    // ---- runtime XCD-aware role negotiation (one-time, verified R6) ----
    if (tid == 0) {
        int x = __builtin_amdgcn_s_getreg(20 | (31 << 11)) & 7;  // HW_REG_XCC_ID
        unsigned slot = atomicAdd(&regcnt[x], 1u);
        asm volatile("s_waitcnt vmcnt(0)" ::: "memory");
        atomicAdd(regtotal, 1u);
        while (ld_sys32(regtotal) < 256u) __builtin_amdgcn_s_sleep(8);
        unsigned cnt[8];
#pragma unroll
        for (int i = 0; i < 8; ++i) cnt[i] = ld_sys32(&regcnt[i]);
        int pure_base = 0, total_pure = 0, lbase = 0;
        for (int i = 0; i < 8; ++i) {
            if (i < x) { pure_base += cnt[i] >> 4; lbase += cnt[i] & 15; }
            total_pure += cnt[i] >> 4;
        }
        int px16 = (int)(cnt[x] >> 4) * 16;
        int bg, jv, sv;
        if ((int)slot < px16) {
            bg = pure_base + ((int)slot >> 4); jv = slot & 15; sv = 0;
        } else {
            int lr = lbase + ((int)slot - px16);
            bg = total_pure + (lr >> 4); jv = lr & 15; sv = 1;
        }
        sh_role[0] = bg; sh_role[1] = jv; sh_role[2] = sv;
    }
    __syncthreads();
    const int bgrp = sh_role[0], jg = sh_role[1];
    const bool sysS = sh_role[2] != 0;
    const int yb = bgrp * 16 + jg;
    unsigned* myflags = flags + bgrp * 64;

    // ---- persistent A fragments: wave w -> j-local = w*8 + jj*2 + ti
    // (lane (lm,q) holds gates of j-local = w*8 + q*2 + ti: the two epilogue
    //  halves (ti=0,1) form one fragment dword -> direct publish)
    v8h afrag[2][21];
    {
        const int jj = lm >> 2, gt = lm & 3;
#pragma unroll
        for (int ti = 0; ti < 2; ++ti) {
            const int grow = gt * kH + jg * 32 + w * 8 + jj * 2 + ti;
#pragma unroll
            for (int kc = 0; kc < 21; ++kc) {
                const int k0 = kc * 32 + q * 8;
                const float* src = (k0 < 160) ? (Wih + grow * 160 + k0)
                                              : (Whh + (size_t)grow * kH + (k0 - 160));
                float4 A = *(const float4*)src;
                float4 Bv = *(const float4*)(src + 4);
                v8h f;
                f[0] = (_Float16)A.x;  f[1] = (_Float16)A.y;
                f[2] = (_Float16)A.z;  f[3] = (_Float16)A.w;
                f[4] = (_Float16)Bv.x; f[5] = (_Float16)Bv.y;
                f[6] = (_Float16)Bv.z; f[7] = (_Float16)Bv.w;
                afrag[ti][kc] = f;
            }
        }
    }
    float biasv[2][4];
    float creg[2];
#pragma unroll
    for (int ti = 0; ti < 2; ++ti) {
        const int jloc = jg * 32 + w * 8 + q * 2 + ti;
#pragma unroll
        for (int g = 0; g < 4; ++g)
            biasv[ti][g] = bih[g * kH + jloc] + bhh[g * kH + jloc];
        creg[ti] = c0[(size_t)(bgrp * 16 + lm) * kH + jloc];
    }

    const float bout0 = bout_p[0];
    const float2 wout2 = *(const float2*)(Wout + 2 * tid);  // y: k = 2*tid
    float4 wout4 = make_float4(0.f, 0.f, 0.f, 0.f);
    if (tid < 128) wout4 = *(const float4*)(Wout + tid * 4);

    // x stager identity (threads 96..255)
    const int st = tid - 96, xb = st & 15, c10 = st >> 4;
    const bool isX = (tid >= 96);
    float4 xr[4];

    auto x_load = [&](int tt) {
        if (isX) {
            const size_t brow = (size_t)(bgrp * 16 + xb) * kT + tt;
            const float* p = (c10 < 8) ? (obs + brow * 128 + c10 * 16)
                                       : (act + brow * 32 + (c10 - 8) * 16);
            xr[0] = *(const float4*)(p);
            xr[1] = *(const float4*)(p + 4);
            xr[2] = *(const float4*)(p + 8);
            xr[3] = *(const float4*)(p + 12);
        }
    };
    auto x_write = [&](char* xbase) {
        if (isX) {
            const int kcx = c10 >> 1;
#pragma unroll
            for (int ii = 0; ii < 2; ++ii) {
                const int qx = (2 * c10 + ii) & 3;
                const int slot = (qx * 16 + xb) ^ kcx;
                float4 a = xr[2 * ii], b = xr[2 * ii + 1];
                v8h f;
                f[0] = (_Float16)a.x; f[1] = (_Float16)a.y;
                f[2] = (_Float16)a.z; f[3] = (_Float16)a.w;
                f[4] = (_Float16)b.x; f[5] = (_Float16)b.y;
                f[6] = (_Float16)b.z; f[7] = (_Float16)b.w;
                *(v8h*)(xbase + kcx * 1024 + slot * 16) = f;
            }
        }
    };

    // ---- preloop: stage x(0) into xbuf[0]; preload x(1) into regs ----
    x_load(0);
    x_write(xbuf[0]);
    x_load(1);
    __syncthreads();

    char* const hfAc = (char*)hfA;
    char* const hfBc = (char*)hfB;

#pragma unroll 1
    for (int t = 0; t < kT; ++t) {
        const char* hsrcB = ((t & 1) ? hfBc : hfAc) + (size_t)bgrp * 16384;
        char* hdstB = ((t & 1) ? hfAc : hfBc) + (size_t)bgrp * 16384;
        const char* xcur = xbuf[t & 1];
        char* hreg = hbuf[t & 1];

        // ---- 1. per-wave poll (parallel detect, no barrier hop) ----
        if (t > 0) {
            const unsigned tgt = (unsigned)t;
            const unsigned* fp = myflags + ln;
            while (true) {
                unsigned v = ld32sc(fp, sysS);
                if (__all((int)(v >= tgt))) break;
            }
        }

        // ---- 2. issue h-stage loads (verbatim 16KB fragment copy) ----
        ull u[8];
#pragma unroll
        for (int k = 0; k < 4; ++k) {
            const ull* sp = (const ull*)(hsrcB + k * 4096 + tid * 16);
            u[2 * k]     = ld64sc(sp, sysS);
            u[2 * k + 1] = ld64sc(sp + 1, sysS);
        }

        // ---- 3. x-part MFMA (kc 0..4) while h loads are in flight ----
        v4f a0 = {biasv[0][0], biasv[0][1], biasv[0][2], biasv[0][3]};
        v4f a1 = {biasv[1][0], biasv[1][1], biasv[1][2], biasv[1][3]};
#pragma unroll
        for (int kc = 0; kc < 5; ++kc) {
            v8h bfr = *(const v8h*)(xcur + kc * 1024 + (ln ^ kc) * 16);
            a0 = __builtin_amdgcn_mfma_f32_16x16x32_f16(afrag[0][kc], bfr, a0, 0, 0, 0);
            a1 = __builtin_amdgcn_mfma_f32_16x16x32_f16(afrag[1][kc], bfr, a1, 0, 0, 0);
        }

        // ---- 4. write staged h to LDS (linear b128); stage x(t+1) ----
#pragma unroll
        for (int k = 0; k < 4; ++k) {
            v2u val = {u[2 * k], u[2 * k + 1]};
            *(v2u*)(hreg + k * 4096 + tid * 16) = val;
        }
        if (t < kT - 1) x_write(xbuf[(t + 1) & 1]);
        __syncthreads();  // S0: h(t) + x(t+1) staged (the only barrier)

        // ---- 5. finalize y(t-2) from last step's partials ----
        if (t >= 2 && tid == 64) {
            const float* yp = ypart[(t - 1) & 1];
            out[(size_t)yb * kT + (t - 2)] = bout0 + yp[0] + yp[1] + yp[2] + yp[3];
        }

        // ---- 6. h-part MFMA (ck 0..15), split-K: 4 independent chains ----
        v4f b0 = {0.f, 0.f, 0.f, 0.f}, b1 = {0.f, 0.f, 0.f, 0.f};
#pragma unroll
        for (int ck = 0; ck < 8; ++ck) {
            v8h bfr = *(const v8h*)(hreg + ck * 1024 + (ln ^ ck) * 16);
            a0 = __builtin_amdgcn_mfma_f32_16x16x32_f16(afrag[0][5 + ck], bfr, a0, 0, 0, 0);
            a1 = __builtin_amdgcn_mfma_f32_16x16x32_f16(afrag[1][5 + ck], bfr, a1, 0, 0, 0);
        }
#pragma unroll
        for (int ck = 8; ck < 16; ++ck) {
            v8h bfr = *(const v8h*)(hreg + ck * 1024 + (ln ^ ck) * 16);
            b0 = __builtin_amdgcn_mfma_f32_16x16x32_f16(afrag[0][5 + ck], bfr, b0, 0, 0, 0);
            b1 = __builtin_amdgcn_mfma_f32_16x16x32_f16(afrag[1][5 + ck], bfr, b1, 0, 0, 0);
        }

        // ---- 7. epilogue + direct fragment-layout publish (per wave) ----
        union { unsigned u32; _Float16 h2[2]; } pk;
#pragma unroll
        for (int ti = 0; ti < 2; ++ti) {
            v4f a = ti ? (a1 + b1) : (a0 + b0);
            float iv = sigf(a[0]), fv = sigf(a[1]);
            float gv = tanhff(a[2]), ov = sigf(a[3]);
            creg[ti] = fmaf(fv, creg[ti], iv * gv);
            pk.h2[ti] = (_Float16)(ov * tanhff(creg[ti]));
        }
        st32sc((unsigned*)(hdstB + jg * 1024 + (w * 16 + (lm ^ jg)) * 16 + q * 4),
               pk.u32, sysS);
        asm volatile("s_waitcnt vmcnt(0)" ::: "memory");  // publish ack (L2 for pure)
        if (ln == 0) st32sc(myflags + jg * 4 + w, (unsigned)(t + 1), sysS);

        // ---- 8. y(t-1) partials (off critical path, post-flag) ----
        if (t > 0) {
            const int k = 2 * tid;
            const int ck = k >> 5, qy = (k >> 3) & 3, e = k & 7;
            const int slot = (qy * 16 + jg) ^ ck;
            union { unsigned uu; _Float16 hh[2]; } cv;
            cv.uu = *(const unsigned*)(hreg + ck * 1024 + slot * 16 + e * 2);
            float p = (float)cv.hh[0] * wout2.x + (float)cv.hh[1] * wout2.y;
#pragma unroll
            for (int s = 32; s; s >>= 1) p += __shfl_xor(p, s);
            if (ln == 0) ypart[t & 1][w] = p;
        }

        // ---- 9. issue x(t+2) loads (consumed at step t+1's x_write) ----
        if (t < kT - 2) x_load(t + 2);
    }

    // ---- tail: out[510] from pending partials; out[511] from h(T) in hfA ----
    if (tid < 64) {
        const unsigned* fp = myflags + ln;
        while (true) {
            unsigned v = ld32sc(fp, sysS);
            if (__all((int)(v >= (unsigned)kT))) break;
            __builtin_amdgcn_s_sleep(1);
        }
    }
    __syncthreads();
    if (tid == 64) {
        const float* yp = ypart[1];  // written at step 511
        out[(size_t)yb * kT + (kT - 2)] = bout0 + yp[0] + yp[1] + yp[2] + yp[3];
    }
    if (tid < 128) {
        const int j0 = tid * 4;
        const int ck = j0 >> 5, qf = (j0 >> 3) & 3, e0 = j0 & 7;
        const int slot = (qf * 16 + jg) ^ ck;
        union { ull uu; _Float16 h4[4]; } cv;
        cv.uu = ld64sc((const ull*)(hfAc + (size_t)bgrp * 16384 + ck * 1024 +
                                    slot * 16 + e0 * 2), sysS);
        float p = (float)cv.h4[0] * wout4.x + (float)cv.h4[1] * wout4.y +
                  (float)cv.h4[2] * wout4.z + (float)cv.h4[3] * wout4.w;
#pragma unroll
        for (int s = 32; s; s >>= 1) p += __shfl_xor(p, s);
        if (ln == 0) ytail[w] = p;
    }
    __syncthreads();
    if (tid == 0) out[(size_t)yb * kT + (kT - 1)] = ytail[0] + ytail[1] + bout0;
}

}  // namespace

extern "C" void kernel_launch(void* const* d_in, const int* in_sizes, int n_in,
                              void* d_out, int out_size, void* d_ws, size_t ws_size,
                              hipStream_t stream) {
    const float* obs  = (const float*)d_in[0];
    const float* act  = (const float*)d_in[1];
    const float* Wih  = (const float*)d_in[2];
    const float* Whh  = (const float*)d_in[3];
    const float* bih  = (const float*)d_in[4];
    const float* bhh  = (const float*)d_in[5];
    const float* Wout = (const float*)d_in[6];
    const float* bout = (const float*)d_in[7];
    const float* h0   = (const float*)d_in[8];
    const float* c0   = (const float*)d_in[9];
    float* out = (float*)d_out;

    char* ws = (char*)d_ws;
    _Float16* hfA = (_Float16*)ws;                 // frag-layout h, 256 KB
    _Float16* hfB = (_Float16*)(ws + 262144);      // frag-layout h, 256 KB
    unsigned* ctrl = (unsigned*)(ws + 524288);     // flags[1024] + regcnt[8] + regtotal

    lstm_init<<<512, 256, 0, stream>>>(h0, hfA, ctrl);
    lstm_persist<<<256, 256, 0, stream>>>(obs, act, Wih, Whh, bih, bhh, Wout, bout,
                                          c0, hfA, hfB, ctrl, out);
}